// Round 1
// baseline (893.838 us; speedup 1.0000x reference)
//
#include <hip/hip_runtime.h>
#include <math.h>

#define HH 128
#define WW 128
#define NPIX 16384
#define CIN 3
#define DD 32
#define QQ 128
#define MM 16
#define NBATCH 2
#define EPSF 1e-8f
#define NEDGE 409600   // 25 * NPIX

// ---------------- conv1: 3x3, 3->32, relu, zero-pad SAME ----------------
__global__ __launch_bounds__(256) void conv1_kernel(
    const float* __restrict__ x, const float* __restrict__ w1,
    const float* __restrict__ b1, float* __restrict__ out)
{
    int g  = blockIdx.x * 256 + threadIdx.x;   // B*N*32 = 1048576
    int oc = g & 31;
    int p  = (g >> 5) & (NPIX - 1);
    int b  = g >> 19;
    int i = p >> 7, j = p & 127;
    float acc = b1[oc];
    #pragma unroll
    for (int dy = 0; dy < 3; dy++) {
        int ii = i + dy - 1;
        if (ii < 0 || ii >= HH) continue;
        #pragma unroll
        for (int dx = 0; dx < 3; dx++) {
            int jj = j + dx - 1;
            if (jj < 0 || jj >= WW) continue;
            const float* xr = x + ((size_t)b * NPIX + ii * WW + jj) * CIN;
            const float* wr = w1 + (size_t)((dy * 3 + dx) * CIN) * DD + oc;
            acc += xr[0] * wr[0];
            acc += xr[1] * wr[DD];
            acc += xr[2] * wr[2 * DD];
        }
    }
    out[g] = fmaxf(acc, 0.0f);
}

// ---------------- conv2: 3x3, 32->32, relu ----------------
__global__ __launch_bounds__(256) void conv2_kernel(
    const float* __restrict__ fin, const float* __restrict__ w2,
    const float* __restrict__ b2, float* __restrict__ out)
{
    int g  = blockIdx.x * 256 + threadIdx.x;
    int oc = g & 31;
    int p  = (g >> 5) & (NPIX - 1);
    int b  = g >> 19;
    int i = p >> 7, j = p & 127;
    float acc = b2[oc];
    for (int dy = 0; dy < 3; dy++) {
        int ii = i + dy - 1;
        if (ii < 0 || ii >= HH) continue;
        for (int dx = 0; dx < 3; dx++) {
            int jj = j + dx - 1;
            if (jj < 0 || jj >= WW) continue;
            const float* fr = fin + ((size_t)b * NPIX + ii * WW + jj) * DD;
            const float* wr = w2 + (size_t)((dy * 3 + dx) * DD) * DD + oc;
            #pragma unroll
            for (int ic = 0; ic < DD; ic += 4) {
                float4 fv = *(const float4*)(fr + ic);
                acc += fv.x * wr[(ic + 0) * DD];
                acc += fv.y * wr[(ic + 1) * DD];
                acc += fv.z * wr[(ic + 2) * DD];
                acc += fv.w * wr[(ic + 3) * DD];
            }
        }
    }
    out[g] = fmaxf(acc, 0.0f);
}

// ---------------- k/q 1x1 projections + row norms ----------------
__global__ __launch_bounds__(256) void kq_kernel(
    const float* __restrict__ fin, const float* __restrict__ wk,
    const float* __restrict__ bk, const float* __restrict__ wq,
    float* __restrict__ ksb, float* __restrict__ qsb,
    float* __restrict__ knorm, float* __restrict__ qnorm)
{
    int g  = blockIdx.x * 256 + threadIdx.x;  // B*N*32
    int oc = g & 31;
    int bp = g >> 5;                          // b*N + p
    const float* fr = fin + (size_t)bp * DD;
    float ak = bk[oc], aq = 0.0f;
    #pragma unroll
    for (int ic = 0; ic < DD; ic += 4) {
        float4 fv = *(const float4*)(fr + ic);
        ak += fv.x * wk[(ic + 0) * DD + oc];
        ak += fv.y * wk[(ic + 1) * DD + oc];
        ak += fv.z * wk[(ic + 2) * DD + oc];
        ak += fv.w * wk[(ic + 3) * DD + oc];
        aq += fv.x * wq[(ic + 0) * DD + oc];
        aq += fv.y * wq[(ic + 1) * DD + oc];
        aq += fv.z * wq[(ic + 2) * DD + oc];
        aq += fv.w * wq[(ic + 3) * DD + oc];
    }
    ksb[g] = ak;
    qsb[g] = aq;
    float ssk = ak * ak, ssq = aq * aq;
    #pragma unroll
    for (int m = 1; m < 32; m <<= 1) {
        ssk += __shfl_xor(ssk, m, 64);
        ssq += __shfl_xor(ssq, m, 64);
    }
    if (oc == 0) {
        knorm[bp] = sqrtf(ssk);
        qnorm[bp] = sqrtf(ssq);
    }
}

// ---------------- edge scores: exp(cosine), partial sums ----------------
__global__ __launch_bounds__(256) void edge_kernel(
    const float* __restrict__ ksb, const float* __restrict__ qsb,
    const float* __restrict__ knorm, const float* __restrict__ qnorm,
    float* __restrict__ wT, float* __restrict__ sums)
{
    // grid: 3200 blocks; 1600 per batch (NEDGE/256 = 1600)
    int b = blockIdx.x / 1600;
    int e = (blockIdx.x % 1600) * 256 + threadIdx.x;   // e = o*N + n
    int o = e >> 14;
    int n = e & (NPIX - 1);
    int i = n >> 7, j = n & 127;
    int di = o / 5 - 2, dj = o % 5 - 2;
    int ci = min(max(i + di, 0), HH - 1);
    int cj = min(max(j + dj, 0), WW - 1);
    int m = ci * WW + cj;
    const float* qrow = qsb + ((size_t)b * NPIX + n) * DD;
    const float* krow = ksb + ((size_t)b * NPIX + m) * DD;
    float dot = 0.0f;
    #pragma unroll
    for (int c = 0; c < DD; c += 4) {
        float4 qv = *(const float4*)(qrow + c);
        float4 kv = *(const float4*)(krow + c);
        dot += qv.x * kv.x + qv.y * kv.y + qv.z * kv.z + qv.w * kv.w;
    }
    float den = fmaxf(qnorm[b * NPIX + n] * knorm[b * NPIX + m], EPSF);
    float es = expf(dot / den);
    wT[(((size_t)b * NPIX + n) << 5) + o] = es;

    // block reduce -> one atomicAdd per block (b is block-uniform)
    float v = es;
    #pragma unroll
    for (int mm = 1; mm < 64; mm <<= 1) v += __shfl_xor(v, mm, 64);
    __shared__ float lds[4];
    if ((threadIdx.x & 63) == 0) lds[threadIdx.x >> 6] = v;
    __syncthreads();
    if (threadIdx.x == 0)
        atomicAdd(&sums[b], lds[0] + lds[1] + lds[2] + lds[3]);
}

// ---------------- normalize weights + build col table ----------------
__global__ __launch_bounds__(256) void norm_kernel(
    float* __restrict__ wT, int* __restrict__ colT,
    const float* __restrict__ sums)
{
    int g = blockIdx.x * 256 + threadIdx.x;   // B*N*32
    int o = g & 31;
    int bn = g >> 5;
    int b = bn >> 14;
    int n = bn & (NPIX - 1);
    float inv = 1.0f / sums[b];
    float wv = 0.0f;
    if (o < 25) wv = wT[g] * inv;
    wT[g] = wv;
    if (b == 0) {
        int i = n >> 7, j = n & 127;
        int oo = (o < 25) ? o : 24;
        int di = oo / 5 - 2, dj = oo % 5 - 2;
        int ci = min(max(i + di, 0), HH - 1);
        int cj = min(max(j + dj, 0), WW - 1);
        colT[(n << 5) + o] = ci * WW + cj;
    }
}

// ---------------- one propagation iteration ----------------
__global__ __launch_bounds__(256) void prop_kernel(
    const float* __restrict__ hin, float* __restrict__ hout,
    const float* __restrict__ wT, const int* __restrict__ colT)
{
    // XCD swizzle: blockIdx%8 -> XCD (heuristic). Each XCD gets a contiguous
    // slab of 4096 nodes (32 image rows) so its gather set (~2.4MB) fits 4MB L2.
    int vb = (blockIdx.x & 7) * 512 + (blockIdx.x >> 3);   // 4096 blocks
    int g  = vb * 256 + threadIdx.x;
    int lane = g & 31;            // channel group: 4 floats each
    int bn = g >> 5;              // b*N + n
    int b  = bn >> 14;
    int n  = bn & (NPIX - 1);
    const float* hb   = hin + (size_t)b * NPIX * QQ;
    const float* wrow = wT + ((size_t)bn << 5);
    const int*   crow = colT + (n << 5);
    float4 acc = {0.f, 0.f, 0.f, 0.f};
    #pragma unroll 5
    for (int o = 0; o < 25; o++) {
        int m   = crow[o];
        float w = wrow[o];
        float4 v = *(const float4*)(hb + (size_t)m * QQ + lane * 4);
        acc.x += w * v.x;
        acc.y += w * v.y;
        acc.z += w * v.z;
        acc.w += w * v.w;
    }
    float ss = acc.x * acc.x + acc.y * acc.y + acc.z * acc.z + acc.w * acc.w;
    #pragma unroll
    for (int mm = 1; mm < 32; mm <<= 1) ss += __shfl_xor(ss, mm, 64);
    float sc = 1.0f / (sqrtf(ss) + EPSF);
    float4 r = {acc.x * sc, acc.y * sc, acc.z * sc, acc.w * sc};
    *(float4*)(hout + (size_t)bn * QQ + lane * 4) = r;
}

// ---------------- mask head: h @ w_mask, softmax(16), transpose ----------------
__global__ __launch_bounds__(256) void mask_kernel(
    const float* __restrict__ h, const float* __restrict__ wm,
    float* __restrict__ out)
{
    __shared__ float wls[QQ * MM];   // 8 KB
    for (int t = threadIdx.x; t < QQ * MM; t += 256) wls[t] = wm[t];
    __syncthreads();
    int g = blockIdx.x * 256 + threadIdx.x;  // B*N = 32768
    int b = g >> 14;
    int n = g & (NPIX - 1);
    const float* hr = h + (size_t)g * QQ;
    float acc[MM];
    #pragma unroll
    for (int m = 0; m < MM; m++) acc[m] = 0.0f;
    for (int c = 0; c < QQ; c += 4) {
        float4 hv = *(const float4*)(hr + c);
        #pragma unroll
        for (int m = 0; m < MM; m++) {
            acc[m] += hv.x * wls[(c + 0) * MM + m];
            acc[m] += hv.y * wls[(c + 1) * MM + m];
            acc[m] += hv.z * wls[(c + 2) * MM + m];
            acc[m] += hv.w * wls[(c + 3) * MM + m];
        }
    }
    float mx = acc[0];
    #pragma unroll
    for (int m = 1; m < MM; m++) mx = fmaxf(mx, acc[m]);
    float s = 0.0f;
    #pragma unroll
    for (int m = 0; m < MM; m++) { acc[m] = expf(acc[m] - mx); s += acc[m]; }
    float inv = 1.0f / s;
    #pragma unroll
    for (int m = 0; m < MM; m++)
        out[(((size_t)(b * MM + m)) << 14) + n] = acc[m] * inv;
}

extern "C" void kernel_launch(void* const* d_in, const int* in_sizes, int n_in,
                              void* d_out, int out_size, void* d_ws, size_t ws_size,
                              hipStream_t stream)
{
    const float* x     = (const float*)d_in[0];
    // d_in[1] = edges (int32) -- unused: row/col are analytic
    const float* w1    = (const float*)d_in[2];
    const float* b1    = (const float*)d_in[3];
    const float* w2    = (const float*)d_in[4];
    const float* b2    = (const float*)d_in[5];
    const float* wk    = (const float*)d_in[6];
    const float* bk    = (const float*)d_in[7];
    const float* wq    = (const float*)d_in[8];
    const float* hinit = (const float*)d_in[9];
    const float* wm    = (const float*)d_in[10];
    float* out = (float*)d_out;

    char* ws = (char*)d_ws;
    size_t off = 0;
    auto alloc = [&](size_t bytes) -> void* {
        void* p = ws + off;
        off += (bytes + 255) & ~(size_t)255;
        return p;
    };
    float* feat1 = (float*)alloc((size_t)NBATCH * NPIX * DD * 4);
    float* feat2 = (float*)alloc((size_t)NBATCH * NPIX * DD * 4);
    float* ksb   = (float*)alloc((size_t)NBATCH * NPIX * DD * 4);
    float* qsb   = (float*)alloc((size_t)NBATCH * NPIX * DD * 4);
    float* knorm = (float*)alloc((size_t)NBATCH * NPIX * 4);
    float* qnorm = (float*)alloc((size_t)NBATCH * NPIX * 4);
    float* wT    = (float*)alloc((size_t)NBATCH * NPIX * 32 * 4);
    int*   colT  = (int*)  alloc((size_t)NPIX * 32 * 4);
    float* sums  = (float*)alloc(256);
    float* hA    = (float*)alloc((size_t)NBATCH * NPIX * QQ * 4);
    float* hB    = (float*)alloc((size_t)NBATCH * NPIX * QQ * 4);

    hipMemsetAsync(sums, 0, 2 * sizeof(float), stream);

    conv1_kernel<<<4096, 256, 0, stream>>>(x, w1, b1, feat1);
    conv2_kernel<<<4096, 256, 0, stream>>>(feat1, w2, b2, feat2);
    kq_kernel<<<4096, 256, 0, stream>>>(feat2, wk, bk, wq, ksb, qsb, knorm, qnorm);
    edge_kernel<<<3200, 256, 0, stream>>>(ksb, qsb, knorm, qnorm, wT, sums);
    norm_kernel<<<4096, 256, 0, stream>>>(wT, colT, sums);

    const float* src = hinit;
    float* dst = hA;
    for (int it = 0; it < 32; it++) {
        prop_kernel<<<4096, 256, 0, stream>>>(src, dst, wT, colT);
        src = dst;
        dst = (dst == hA) ? hB : hA;
    }
    mask_kernel<<<128, 256, 0, stream>>>(src, wm, out);
}

// Round 2
// 547.596 us; speedup vs baseline: 1.6323x; 1.6323x over previous
//
#include <hip/hip_runtime.h>
#include <math.h>

#define HH 128
#define WW 128
#define NPIX 16384
#define CIN 3
#define DD 32
#define QQ 128
#define MM 16
#define NBATCH 2
#define EPSF 1e-8f

// ---------------- conv1: 3x3, 3->32, relu, zero-pad SAME ----------------
// thread = (pixel, oc-quad of 8); weights in LDS (broadcast); 512 blocks.
__global__ __launch_bounds__(256) void conv1_kernel(
    const float* __restrict__ x, const float* __restrict__ w1,
    const float* __restrict__ b1, float* __restrict__ out)
{
    __shared__ float wlds[9 * CIN * DD];   // 864 floats = 3.4 KB
    int t = threadIdx.x;
    for (int idx = t; idx < 9 * CIN * DD / 4; idx += 256)
        ((float4*)wlds)[idx] = ((const float4*)w1)[idx];
    __syncthreads();

    int ocq = t & 3;
    int pl  = t >> 2;                       // 0..63
    int blk = blockIdx.x;                   // 512
    int b   = blk >> 8;
    int pix = (blk & 255) * 64 + pl;
    int i = pix >> 7, j = pix & 127;
    int ocb = ocq << 3;

    float4 acc0 = *(const float4*)(b1 + ocb);
    float4 acc1 = *(const float4*)(b1 + ocb + 4);
    #pragma unroll
    for (int dy = 0; dy < 3; dy++) {
        int ii = i + dy - 1;
        if (ii < 0 || ii >= HH) continue;
        #pragma unroll
        for (int dx = 0; dx < 3; dx++) {
            int jj = j + dx - 1;
            if (jj < 0 || jj >= WW) continue;
            const float* fr = x + ((size_t)((b << 14) + ii * WW + jj)) * CIN;
            float in0 = fr[0], in1 = fr[1], in2 = fr[2];
            const float* wp = wlds + (size_t)((dy * 3 + dx) * CIN) * DD + ocb;
            #pragma unroll
            for (int ic = 0; ic < 3; ic++) {
                float inv = (ic == 0) ? in0 : (ic == 1) ? in1 : in2;
                float4 w0 = *(const float4*)(wp + ic * DD);
                float4 w1v = *(const float4*)(wp + ic * DD + 4);
                acc0.x += inv * w0.x;  acc0.y += inv * w0.y;
                acc0.z += inv * w0.z;  acc0.w += inv * w0.w;
                acc1.x += inv * w1v.x; acc1.y += inv * w1v.y;
                acc1.z += inv * w1v.z; acc1.w += inv * w1v.w;
            }
        }
    }
    float* op = out + (((size_t)(b << 14) + pix) << 5) + ocb;
    float4 r0 = {fmaxf(acc0.x, 0.f), fmaxf(acc0.y, 0.f), fmaxf(acc0.z, 0.f), fmaxf(acc0.w, 0.f)};
    float4 r1 = {fmaxf(acc1.x, 0.f), fmaxf(acc1.y, 0.f), fmaxf(acc1.z, 0.f), fmaxf(acc1.w, 0.f)};
    *(float4*)op = r0;
    *(float4*)(op + 4) = r1;
}

// ---------------- conv2: 3x3, 32->32, relu ----------------
// thread = (pixel, oc-quad of 8); weights in LDS; inputs from L1 reused x8.
__global__ __launch_bounds__(256) void conv2_kernel(
    const float* __restrict__ fin, const float* __restrict__ w2,
    const float* __restrict__ b2, float* __restrict__ out)
{
    __shared__ float wlds[9 * DD * DD];    // 9216 floats = 36.9 KB
    int t = threadIdx.x;
    for (int idx = t; idx < 9 * DD * DD / 4; idx += 256)
        ((float4*)wlds)[idx] = ((const float4*)w2)[idx];
    __syncthreads();

    int ocq = t & 3;
    int pl  = t >> 2;
    int blk = blockIdx.x;                   // 512
    int b   = blk >> 8;
    int pix = (blk & 255) * 64 + pl;
    int i = pix >> 7, j = pix & 127;
    int ocb = ocq << 3;

    float4 acc0 = *(const float4*)(b2 + ocb);
    float4 acc1 = *(const float4*)(b2 + ocb + 4);
    #pragma unroll
    for (int dy = 0; dy < 3; dy++) {
        int ii = i + dy - 1;
        if (ii < 0 || ii >= HH) continue;
        #pragma unroll
        for (int dx = 0; dx < 3; dx++) {
            int jj = j + dx - 1;
            if (jj < 0 || jj >= WW) continue;
            const float* fr = fin + (((size_t)(b << 14) + ii * WW + jj)) * DD;
            float iv[DD];
            #pragma unroll
            for (int c = 0; c < DD / 4; c++)
                ((float4*)iv)[c] = *(const float4*)(fr + c * 4);
            const float* wp = wlds + (size_t)((dy * 3 + dx) * DD) * DD + ocb;
            #pragma unroll
            for (int ic = 0; ic < DD; ic++) {
                float inv = iv[ic];
                float4 w0 = *(const float4*)(wp + ic * DD);
                float4 w1v = *(const float4*)(wp + ic * DD + 4);
                acc0.x += inv * w0.x;  acc0.y += inv * w0.y;
                acc0.z += inv * w0.z;  acc0.w += inv * w0.w;
                acc1.x += inv * w1v.x; acc1.y += inv * w1v.y;
                acc1.z += inv * w1v.z; acc1.w += inv * w1v.w;
            }
        }
    }
    float* op = out + (((size_t)(b << 14) + pix) << 5) + ocb;
    float4 r0 = {fmaxf(acc0.x, 0.f), fmaxf(acc0.y, 0.f), fmaxf(acc0.z, 0.f), fmaxf(acc0.w, 0.f)};
    float4 r1 = {fmaxf(acc1.x, 0.f), fmaxf(acc1.y, 0.f), fmaxf(acc1.z, 0.f), fmaxf(acc1.w, 0.f)};
    *(float4*)op = r0;
    *(float4*)(op + 4) = r1;
}

// ---------------- k/q 1x1 projections + row norms ----------------
__global__ __launch_bounds__(256) void kq_kernel(
    const float* __restrict__ fin, const float* __restrict__ wk,
    const float* __restrict__ bk, const float* __restrict__ wq,
    float* __restrict__ ksb, float* __restrict__ qsb,
    float* __restrict__ knorm, float* __restrict__ qnorm)
{
    int g  = blockIdx.x * 256 + threadIdx.x;  // B*N*32
    int oc = g & 31;
    int bp = g >> 5;
    const float* fr = fin + (size_t)bp * DD;
    float ak = bk[oc], aq = 0.0f;
    #pragma unroll
    for (int ic = 0; ic < DD; ic += 4) {
        float4 fv = *(const float4*)(fr + ic);
        ak += fv.x * wk[(ic + 0) * DD + oc];
        ak += fv.y * wk[(ic + 1) * DD + oc];
        ak += fv.z * wk[(ic + 2) * DD + oc];
        ak += fv.w * wk[(ic + 3) * DD + oc];
        aq += fv.x * wq[(ic + 0) * DD + oc];
        aq += fv.y * wq[(ic + 1) * DD + oc];
        aq += fv.z * wq[(ic + 2) * DD + oc];
        aq += fv.w * wq[(ic + 3) * DD + oc];
    }
    ksb[g] = ak;
    qsb[g] = aq;
    float ssk = ak * ak, ssq = aq * aq;
    #pragma unroll
    for (int m = 1; m < 32; m <<= 1) {
        ssk += __shfl_xor(ssk, m, 64);
        ssq += __shfl_xor(ssq, m, 64);
    }
    if (oc == 0) {
        knorm[bp] = sqrtf(ssk);
        qnorm[bp] = sqrtf(ssq);
    }
}

// ---------------- edge scores: exp(cosine), per-batch sums ----------------
__global__ __launch_bounds__(256) void edge_kernel(
    const float* __restrict__ ksb, const float* __restrict__ qsb,
    const float* __restrict__ knorm, const float* __restrict__ qnorm,
    float* __restrict__ wT, float* __restrict__ sums)
{
    int b = blockIdx.x / 1600;
    int e = (blockIdx.x % 1600) * 256 + threadIdx.x;   // e = o*N + n
    int o = e >> 14;
    int n = e & (NPIX - 1);
    int i = n >> 7, j = n & 127;
    int di = o / 5 - 2, dj = o % 5 - 2;
    int ci = min(max(i + di, 0), HH - 1);
    int cj = min(max(j + dj, 0), WW - 1);
    int m = ci * WW + cj;
    const float* qrow = qsb + ((size_t)b * NPIX + n) * DD;
    const float* krow = ksb + ((size_t)b * NPIX + m) * DD;
    float dot = 0.0f;
    #pragma unroll
    for (int c = 0; c < DD; c += 4) {
        float4 qv = *(const float4*)(qrow + c);
        float4 kv = *(const float4*)(krow + c);
        dot += qv.x * kv.x + qv.y * kv.y + qv.z * kv.z + qv.w * kv.w;
    }
    float den = fmaxf(qnorm[b * NPIX + n] * knorm[b * NPIX + m], EPSF);
    float es = expf(dot / den);  // cosine in [-1,1]: no max-subtraction needed
    wT[(((size_t)b * NPIX + n) << 5) + o] = es;

    float v = es;
    #pragma unroll
    for (int mm = 1; mm < 64; mm <<= 1) v += __shfl_xor(v, mm, 64);
    __shared__ float lds[4];
    if ((threadIdx.x & 63) == 0) lds[threadIdx.x >> 6] = v;
    __syncthreads();
    if (threadIdx.x == 0)
        atomicAdd(&sums[b], lds[0] + lds[1] + lds[2] + lds[3]);
}

// ---------------- one propagation iteration: LDS-tiled ----------------
// Block = 8x8 node tile (one batch). LDS holds 12x12 pixel rows (2-halo),
// 64 channels per slab (2 slabs). Thread (g=t>>4, s=t&15): node column
// q=g&7, row-block rb=g>>3 (4 nodes), channel slot s (float4). Column
// register-blocking: each staged float4 feeds up to 4 node accumulators.
__global__ __launch_bounds__(256) void prop_kernel(
    const float* __restrict__ hin, float* __restrict__ hout,
    const float* __restrict__ wT, const float* __restrict__ sums)
{
    __shared__ float4 tile_s[144 * 17];    // 12x12 pixels x 16 slots, pad 17
    __shared__ float wts[64][25];          // softmax weights, pre-scaled
    const int t   = threadIdx.x;
    const int blk = blockIdx.x;            // 512
    const int b   = blk >> 8;
    const int tl  = blk & 255;
    const int ti0 = (tl >> 4) << 3;
    const int tj0 = (tl & 15) << 3;

    if (t < 64) {
        float invs = 1.0f / sums[b];
        int p = t >> 3, qq = t & 7;
        int gp = (ti0 + p) * WW + (tj0 + qq);
        const float* wrow = wT + (((size_t)(b << 14) + gp) << 5);
        #pragma unroll
        for (int o = 0; o < 25; o++) wts[t][o] = wrow[o] * invs;
    }

    const int s  = t & 15;
    const int g  = t >> 4;
    const int q  = g & 7;
    const int rb = g >> 3;
    const float* hb = hin + ((size_t)b << 21);

    float4 acc[2][4];
    #pragma unroll
    for (int sl = 0; sl < 2; sl++)
        #pragma unroll
        for (int k = 0; k < 4; k++) acc[sl][k] = {0.f, 0.f, 0.f, 0.f};

    #pragma unroll
    for (int sl = 0; sl < 2; sl++) {
        if (sl) __syncthreads();           // WAR: slab0 reads done
        int c0 = sl << 6;
        #pragma unroll
        for (int a0 = 0; a0 < 144; a0 += 16) {
            int a = a0 + g;
            int ar = a / 12, ac = a - ar * 12;
            int gi = min(max(ti0 + ar - 2, 0), HH - 1);
            int gj = min(max(tj0 + ac - 2, 0), WW - 1);
            tile_s[a * 17 + s] =
                *(const float4*)(hb + ((size_t)(gi * WW + gj) << 7) + c0 + (s << 2));
        }
        __syncthreads();

        #pragma unroll
        for (int dj = 0; dj < 5; dj++) {
            int ccol = q + dj;
            #pragma unroll
            for (int a = 0; a < 8; a++) {
                int trow = (rb << 2) + a;
                float4 v = tile_s[(trow * 12 + ccol) * 17 + s];
                #pragma unroll
                for (int k = 0; k < 4; k++) {
                    if (k < a - 4 || k > a) continue;   // compile-time pruned
                    int nl = (((rb << 2) + k) << 3) + q;
                    float w = wts[nl][(a - k) * 5 + dj];
                    acc[sl][k].x += w * v.x;
                    acc[sl][k].y += w * v.y;
                    acc[sl][k].z += w * v.z;
                    acc[sl][k].w += w * v.w;
                }
            }
        }
    }

    #pragma unroll
    for (int k = 0; k < 4; k++) {
        float ss = acc[0][k].x * acc[0][k].x + acc[0][k].y * acc[0][k].y +
                   acc[0][k].z * acc[0][k].z + acc[0][k].w * acc[0][k].w +
                   acc[1][k].x * acc[1][k].x + acc[1][k].y * acc[1][k].y +
                   acc[1][k].z * acc[1][k].z + acc[1][k].w * acc[1][k].w;
        ss += __shfl_xor(ss, 1, 64);
        ss += __shfl_xor(ss, 2, 64);
        ss += __shfl_xor(ss, 4, 64);
        ss += __shfl_xor(ss, 8, 64);
        float rs = 1.0f / (sqrtf(ss) + EPSF);
        int gp = (ti0 + (rb << 2) + k) * WW + (tj0 + q);
        float* orow = hout + (((size_t)(b << 14) + gp) << 7);
        float4 r0 = {acc[0][k].x * rs, acc[0][k].y * rs, acc[0][k].z * rs, acc[0][k].w * rs};
        float4 r1 = {acc[1][k].x * rs, acc[1][k].y * rs, acc[1][k].z * rs, acc[1][k].w * rs};
        *(float4*)(orow + (s << 2)) = r0;
        *(float4*)(orow + 64 + (s << 2)) = r1;
    }
}

// ---------------- mask head: h @ w_mask, softmax(16), transpose ----------------
__global__ __launch_bounds__(128) void mask_kernel(
    const float* __restrict__ h, const float* __restrict__ wm,
    float* __restrict__ out)
{
    __shared__ float wls[QQ * MM];   // 8 KB
    for (int t = threadIdx.x; t < QQ * MM; t += 128) wls[t] = wm[t];
    __syncthreads();
    int g = blockIdx.x * 128 + threadIdx.x;  // B*N = 32768
    int b = g >> 14;
    int n = g & (NPIX - 1);
    const float* hr = h + (size_t)g * QQ;
    float acc[MM];
    #pragma unroll
    for (int m = 0; m < MM; m++) acc[m] = 0.0f;
    for (int c = 0; c < QQ; c += 4) {
        float4 hv = *(const float4*)(hr + c);
        #pragma unroll
        for (int m = 0; m < MM; m++) {
            acc[m] += hv.x * wls[(c + 0) * MM + m];
            acc[m] += hv.y * wls[(c + 1) * MM + m];
            acc[m] += hv.z * wls[(c + 2) * MM + m];
            acc[m] += hv.w * wls[(c + 3) * MM + m];
        }
    }
    float mx = acc[0];
    #pragma unroll
    for (int m = 1; m < MM; m++) mx = fmaxf(mx, acc[m]);
    float sum = 0.0f;
    #pragma unroll
    for (int m = 0; m < MM; m++) { acc[m] = expf(acc[m] - mx); sum += acc[m]; }
    float inv = 1.0f / sum;
    #pragma unroll
    for (int m = 0; m < MM; m++)
        out[(((size_t)(b * MM + m)) << 14) + n] = acc[m] * inv;
}

extern "C" void kernel_launch(void* const* d_in, const int* in_sizes, int n_in,
                              void* d_out, int out_size, void* d_ws, size_t ws_size,
                              hipStream_t stream)
{
    const float* x     = (const float*)d_in[0];
    // d_in[1] = edges (int32) -- unused: row/col are analytic
    const float* w1    = (const float*)d_in[2];
    const float* b1    = (const float*)d_in[3];
    const float* w2    = (const float*)d_in[4];
    const float* b2    = (const float*)d_in[5];
    const float* wk    = (const float*)d_in[6];
    const float* bk    = (const float*)d_in[7];
    const float* wq    = (const float*)d_in[8];
    const float* hinit = (const float*)d_in[9];
    const float* wm    = (const float*)d_in[10];
    float* out = (float*)d_out;

    char* ws = (char*)d_ws;
    size_t off = 0;
    auto alloc = [&](size_t bytes) -> void* {
        void* p = ws + off;
        off += (bytes + 255) & ~(size_t)255;
        return p;
    };
    float* feat1 = (float*)alloc((size_t)NBATCH * NPIX * DD * 4);
    float* feat2 = (float*)alloc((size_t)NBATCH * NPIX * DD * 4);
    float* ksb   = (float*)alloc((size_t)NBATCH * NPIX * DD * 4);
    float* qsb   = (float*)alloc((size_t)NBATCH * NPIX * DD * 4);
    float* knorm = (float*)alloc((size_t)NBATCH * NPIX * 4);
    float* qnorm = (float*)alloc((size_t)NBATCH * NPIX * 4);
    float* wT    = (float*)alloc((size_t)NBATCH * NPIX * 32 * 4);
    float* sums  = (float*)alloc(256);
    float* hA    = (float*)alloc((size_t)NBATCH * NPIX * QQ * 4);
    float* hB    = (float*)alloc((size_t)NBATCH * NPIX * QQ * 4);

    hipMemsetAsync(sums, 0, 2 * sizeof(float), stream);

    conv1_kernel<<<512, 256, 0, stream>>>(x, w1, b1, feat1);
    conv2_kernel<<<512, 256, 0, stream>>>(feat1, w2, b2, feat2);
    kq_kernel<<<4096, 256, 0, stream>>>(feat2, wk, bk, wq, ksb, qsb, knorm, qnorm);
    edge_kernel<<<3200, 256, 0, stream>>>(ksb, qsb, knorm, qnorm, wT, sums);

    const float* src = hinit;
    float* dst = hA;
    for (int it = 0; it < 32; it++) {
        prop_kernel<<<512, 256, 0, stream>>>(src, dst, wT, sums);
        src = dst;
        dst = (dst == hA) ? hB : hA;
    }
    mask_kernel<<<256, 128, 0, stream>>>(src, wm, out);
}

// Round 3
// 492.958 us; speedup vs baseline: 1.8132x; 1.1108x over previous
//
#include <hip/hip_runtime.h>
#include <math.h>

#define HH 128
#define WW 128
#define NPIX 16384
#define CIN 3
#define DD 32
#define QQ 128
#define MM 16
#define NBATCH 2
#define EPSF 1e-8f

// ---------------- conv1: 3x3, 3->32, relu, zero-pad SAME ----------------
__global__ __launch_bounds__(256) void conv1_kernel(
    const float* __restrict__ x, const float* __restrict__ w1,
    const float* __restrict__ b1, float* __restrict__ out)
{
    __shared__ float wlds[9 * CIN * DD];
    int t = threadIdx.x;
    for (int idx = t; idx < 9 * CIN * DD / 4; idx += 256)
        ((float4*)wlds)[idx] = ((const float4*)w1)[idx];
    __syncthreads();

    int ocq = t & 3;
    int pl  = t >> 2;
    int blk = blockIdx.x;                   // 512
    int b   = blk >> 8;
    int pix = (blk & 255) * 64 + pl;
    int i = pix >> 7, j = pix & 127;
    int ocb = ocq << 3;

    float4 acc0 = *(const float4*)(b1 + ocb);
    float4 acc1 = *(const float4*)(b1 + ocb + 4);
    #pragma unroll
    for (int dy = 0; dy < 3; dy++) {
        int ii = i + dy - 1;
        if (ii < 0 || ii >= HH) continue;
        #pragma unroll
        for (int dx = 0; dx < 3; dx++) {
            int jj = j + dx - 1;
            if (jj < 0 || jj >= WW) continue;
            const float* fr = x + ((size_t)((b << 14) + ii * WW + jj)) * CIN;
            float in0 = fr[0], in1 = fr[1], in2 = fr[2];
            const float* wp = wlds + (size_t)((dy * 3 + dx) * CIN) * DD + ocb;
            #pragma unroll
            for (int ic = 0; ic < 3; ic++) {
                float inv = (ic == 0) ? in0 : (ic == 1) ? in1 : in2;
                float4 w0 = *(const float4*)(wp + ic * DD);
                float4 w1v = *(const float4*)(wp + ic * DD + 4);
                acc0.x += inv * w0.x;  acc0.y += inv * w0.y;
                acc0.z += inv * w0.z;  acc0.w += inv * w0.w;
                acc1.x += inv * w1v.x; acc1.y += inv * w1v.y;
                acc1.z += inv * w1v.z; acc1.w += inv * w1v.w;
            }
        }
    }
    float* op = out + (((size_t)(b << 14) + pix) << 5) + ocb;
    float4 r0 = {fmaxf(acc0.x, 0.f), fmaxf(acc0.y, 0.f), fmaxf(acc0.z, 0.f), fmaxf(acc0.w, 0.f)};
    float4 r1 = {fmaxf(acc1.x, 0.f), fmaxf(acc1.y, 0.f), fmaxf(acc1.z, 0.f), fmaxf(acc1.w, 0.f)};
    *(float4*)op = r0;
    *(float4*)(op + 4) = r1;
}

// ---------------- conv2: 3x3, 32->32, relu ----------------
__global__ __launch_bounds__(256) void conv2_kernel(
    const float* __restrict__ fin, const float* __restrict__ w2,
    const float* __restrict__ b2, float* __restrict__ out)
{
    __shared__ float wlds[9 * DD * DD];    // 36.9 KB
    int t = threadIdx.x;
    for (int idx = t; idx < 9 * DD * DD / 4; idx += 256)
        ((float4*)wlds)[idx] = ((const float4*)w2)[idx];
    __syncthreads();

    int ocq = t & 3;
    int pl  = t >> 2;
    int blk = blockIdx.x;                   // 512
    int b   = blk >> 8;
    int pix = (blk & 255) * 64 + pl;
    int i = pix >> 7, j = pix & 127;
    int ocb = ocq << 3;

    float4 acc0 = *(const float4*)(b2 + ocb);
    float4 acc1 = *(const float4*)(b2 + ocb + 4);
    #pragma unroll
    for (int dy = 0; dy < 3; dy++) {
        int ii = i + dy - 1;
        if (ii < 0 || ii >= HH) continue;
        #pragma unroll
        for (int dx = 0; dx < 3; dx++) {
            int jj = j + dx - 1;
            if (jj < 0 || jj >= WW) continue;
            const float* fr = fin + (((size_t)(b << 14) + ii * WW + jj)) * DD;
            float iv[DD];
            #pragma unroll
            for (int c = 0; c < DD / 4; c++)
                ((float4*)iv)[c] = *(const float4*)(fr + c * 4);
            const float* wp = wlds + (size_t)((dy * 3 + dx) * DD) * DD + ocb;
            #pragma unroll
            for (int ic = 0; ic < DD; ic++) {
                float inv = iv[ic];
                float4 w0 = *(const float4*)(wp + ic * DD);
                float4 w1v = *(const float4*)(wp + ic * DD + 4);
                acc0.x += inv * w0.x;  acc0.y += inv * w0.y;
                acc0.z += inv * w0.z;  acc0.w += inv * w0.w;
                acc1.x += inv * w1v.x; acc1.y += inv * w1v.y;
                acc1.z += inv * w1v.z; acc1.w += inv * w1v.w;
            }
        }
    }
    float* op = out + (((size_t)(b << 14) + pix) << 5) + ocb;
    float4 r0 = {fmaxf(acc0.x, 0.f), fmaxf(acc0.y, 0.f), fmaxf(acc0.z, 0.f), fmaxf(acc0.w, 0.f)};
    float4 r1 = {fmaxf(acc1.x, 0.f), fmaxf(acc1.y, 0.f), fmaxf(acc1.z, 0.f), fmaxf(acc1.w, 0.f)};
    *(float4*)op = r0;
    *(float4*)(op + 4) = r1;
}

// ---------------- k/q 1x1 projections + row norms ----------------
__global__ __launch_bounds__(256) void kq_kernel(
    const float* __restrict__ fin, const float* __restrict__ wk,
    const float* __restrict__ bk, const float* __restrict__ wq,
    float* __restrict__ ksb, float* __restrict__ qsb,
    float* __restrict__ knorm, float* __restrict__ qnorm)
{
    int g  = blockIdx.x * 256 + threadIdx.x;  // B*N*32
    int oc = g & 31;
    int bp = g >> 5;
    const float* fr = fin + (size_t)bp * DD;
    float ak = bk[oc], aq = 0.0f;
    #pragma unroll
    for (int ic = 0; ic < DD; ic += 4) {
        float4 fv = *(const float4*)(fr + ic);
        ak += fv.x * wk[(ic + 0) * DD + oc];
        ak += fv.y * wk[(ic + 1) * DD + oc];
        ak += fv.z * wk[(ic + 2) * DD + oc];
        ak += fv.w * wk[(ic + 3) * DD + oc];
        aq += fv.x * wq[(ic + 0) * DD + oc];
        aq += fv.y * wq[(ic + 1) * DD + oc];
        aq += fv.z * wq[(ic + 2) * DD + oc];
        aq += fv.w * wq[(ic + 3) * DD + oc];
    }
    ksb[g] = ak;
    qsb[g] = aq;
    float ssk = ak * ak, ssq = aq * aq;
    #pragma unroll
    for (int m = 1; m < 32; m <<= 1) {
        ssk += __shfl_xor(ssk, m, 64);
        ssq += __shfl_xor(ssq, m, 64);
    }
    if (oc == 0) {
        knorm[bp] = sqrtf(ssk);
        qnorm[bp] = sqrtf(ssq);
    }
}

// ---------------- edge scores: LDS-tiled exp(cosine) + per-batch sums ----
// Block = 8x8 node tile. k halo (12x12 rows) + q tile + norms staged in LDS
// with coalesced float4 loads. Thread (nl = t>>2, s = t&3) computes offsets
// o = s, s+4, ... (25-neighborhood).
__global__ __launch_bounds__(256) void edge_kernel(
    const float* __restrict__ ksb, const float* __restrict__ qsb,
    const float* __restrict__ knorm, const float* __restrict__ qnorm,
    float* __restrict__ wT, float* __restrict__ sums)
{
    __shared__ float kt[144][36];   // +4 pad: breaks 32-stride bank aliasing
    __shared__ float qt[64][36];
    __shared__ float kn[144];
    __shared__ float qn[64];
    __shared__ float red[4];
    const int t   = threadIdx.x;
    const int blk = blockIdx.x;     // 512
    const int b   = blk >> 8;
    const int tl  = blk & 255;
    const int ti0 = (tl >> 4) << 3, tj0 = (tl & 15) << 3;
    const float* kb = ksb + ((size_t)b << 19);
    const float* qb = qsb + ((size_t)b << 19);

    for (int idx = t; idx < 144 * 8; idx += 256) {
        int row = idx >> 3, quad = idx & 7;
        int ar = row / 12, ac = row - ar * 12;
        int gi = min(max(ti0 + ar - 2, 0), HH - 1);
        int gj = min(max(tj0 + ac - 2, 0), WW - 1);
        *(float4*)&kt[row][quad << 2] =
            *(const float4*)(kb + ((size_t)(gi * WW + gj) << 5) + (quad << 2));
    }
    for (int idx = t; idx < 64 * 8; idx += 256) {
        int row = idx >> 3, quad = idx & 7;
        int gp = (ti0 + (row >> 3)) * WW + tj0 + (row & 7);
        *(float4*)&qt[row][quad << 2] =
            *(const float4*)(qb + ((size_t)gp << 5) + (quad << 2));
    }
    if (t < 144) {
        int ar = t / 12, ac = t - ar * 12;
        int gi = min(max(ti0 + ar - 2, 0), HH - 1);
        int gj = min(max(tj0 + ac - 2, 0), WW - 1);
        kn[t] = knorm[(b << 14) + gi * WW + gj];
    } else if (t < 208) {
        int r2 = t - 144;
        int gp = (ti0 + (r2 >> 3)) * WW + tj0 + (r2 & 7);
        qn[r2] = qnorm[(b << 14) + gp];
    }
    __syncthreads();

    const int nl = t >> 2, s = t & 3;
    const int p = nl >> 3, q = nl & 7;
    float4 qv[8];
    #pragma unroll
    for (int c = 0; c < 8; c++) qv[c] = *(const float4*)&qt[nl][c << 2];
    const float qnv = qn[nl];
    const int gp = (ti0 + p) * WW + tj0 + q;
    float* wrow = wT + (((size_t)(b << 14) + gp) << 5);
    float lsum = 0.0f;
    for (int o = s; o < 25; o += 4) {
        int di = o / 5, dj = o - di * 5;      // 0..4
        int krow = (p + di) * 12 + (q + dj);  // halo coords
        const float* kr = &kt[krow][0];
        float dot = 0.0f;
        #pragma unroll
        for (int c = 0; c < 8; c++) {
            float4 kv = *(const float4*)(kr + (c << 2));
            dot += qv[c].x * kv.x + qv[c].y * kv.y + qv[c].z * kv.z + qv[c].w * kv.w;
        }
        float den = fmaxf(qnv * kn[krow], EPSF);
        float es = expf(dot / den);   // cosine in [-1,1]: no max-sub needed
        wrow[o] = es;
        lsum += es;
    }
    #pragma unroll
    for (int mm = 1; mm < 64; mm <<= 1) lsum += __shfl_xor(lsum, mm, 64);
    if ((t & 63) == 0) red[t >> 6] = lsum;
    __syncthreads();
    if (t == 0) atomicAdd(&sums[b], red[0] + red[1] + red[2] + red[3]);
}

// ---------------- one propagation iteration: LDS-tiled + XCD slabs -------
// blockIdx&7 -> XCD (round-robin heuristic): XCD x owns 4 contiguous global
// tile-rows (32x128px slab, ~5MB w/ wT) so iter-to-iter h reuse stays in its
// 4MB L2. Coalesced wts staging across all 256 threads.
__global__ __launch_bounds__(256) void prop_kernel(
    const float* __restrict__ hin, float* __restrict__ hout,
    const float* __restrict__ wT, const float* __restrict__ sums)
{
    __shared__ float4 tile_s[144 * 17];    // 12x12 pixels x 16 slots, pad 17
    __shared__ float wts[64][36];          // pre-scaled softmax weights
    const int t = threadIdx.x;
    const int x = blockIdx.x & 7;          // XCD slab
    const int r = blockIdx.x >> 3;         // 0..63 within slab
    const int g_tr = (x << 2) + (r >> 4);  // global tile-row 0..31
    const int b   = g_tr >> 4;
    const int ti0 = (g_tr & 15) << 3;
    const int tj0 = (r & 15) << 3;

    // coalesced wts staging: 8 tile-rows x 256 consecutive floats
    {
        float invs = 1.0f / sums[b];
        const float* wbase = wT + (((size_t)(b << 14) + ti0 * WW + tj0) << 5);
        for (int idx = t; idx < 512; idx += 256) {
            int p = idx >> 6, rest = idx & 63;
            float4 v = *(const float4*)(wbase + (((size_t)p * WW) << 5) + (rest << 2));
            int nl = (p << 3) + (rest >> 3);
            int c4 = (rest & 7) << 2;
            float4 sv = {v.x * invs, v.y * invs, v.z * invs, v.w * invs};
            *(float4*)&wts[nl][c4] = sv;
        }
    }

    const int s  = t & 15;
    const int g  = t >> 4;
    const int q  = g & 7;
    const int rb = g >> 3;
    const float* hb = hin + ((size_t)b << 21);

    float4 acc[2][4];
    #pragma unroll
    for (int sl = 0; sl < 2; sl++)
        #pragma unroll
        for (int k = 0; k < 4; k++) acc[sl][k] = {0.f, 0.f, 0.f, 0.f};

    #pragma unroll
    for (int sl = 0; sl < 2; sl++) {
        if (sl) __syncthreads();           // WAR: slab0 reads done
        int c0 = sl << 6;
        #pragma unroll
        for (int a0 = 0; a0 < 144; a0 += 16) {
            int a = a0 + g;
            int ar = a / 12, ac = a - ar * 12;
            int gi = min(max(ti0 + ar - 2, 0), HH - 1);
            int gj = min(max(tj0 + ac - 2, 0), WW - 1);
            tile_s[a * 17 + s] =
                *(const float4*)(hb + ((size_t)(gi * WW + gj) << 7) + c0 + (s << 2));
        }
        __syncthreads();

        #pragma unroll
        for (int dj = 0; dj < 5; dj++) {
            int ccol = q + dj;
            #pragma unroll
            for (int a = 0; a < 8; a++) {
                int trow = (rb << 2) + a;
                float4 v = tile_s[(trow * 12 + ccol) * 17 + s];
                #pragma unroll
                for (int k = 0; k < 4; k++) {
                    if (k < a - 4 || k > a) continue;   // compile-time pruned
                    int nl = (((rb << 2) + k) << 3) + q;
                    float w = wts[nl][(a - k) * 5 + dj];
                    acc[sl][k].x += w * v.x;
                    acc[sl][k].y += w * v.y;
                    acc[sl][k].z += w * v.z;
                    acc[sl][k].w += w * v.w;
                }
            }
        }
    }

    #pragma unroll
    for (int k = 0; k < 4; k++) {
        float ss = acc[0][k].x * acc[0][k].x + acc[0][k].y * acc[0][k].y +
                   acc[0][k].z * acc[0][k].z + acc[0][k].w * acc[0][k].w +
                   acc[1][k].x * acc[1][k].x + acc[1][k].y * acc[1][k].y +
                   acc[1][k].z * acc[1][k].z + acc[1][k].w * acc[1][k].w;
        ss += __shfl_xor(ss, 1, 64);
        ss += __shfl_xor(ss, 2, 64);
        ss += __shfl_xor(ss, 4, 64);
        ss += __shfl_xor(ss, 8, 64);
        float rs = 1.0f / (sqrtf(ss) + EPSF);
        int gp = (ti0 + (rb << 2) + k) * WW + (tj0 + q);
        float* orow = hout + (((size_t)(b << 14) + gp) << 7);
        float4 r0 = {acc[0][k].x * rs, acc[0][k].y * rs, acc[0][k].z * rs, acc[0][k].w * rs};
        float4 r1 = {acc[1][k].x * rs, acc[1][k].y * rs, acc[1][k].z * rs, acc[1][k].w * rs};
        *(float4*)(orow + (s << 2)) = r0;
        *(float4*)(orow + 64 + (s << 2)) = r1;
    }
}

// ---------------- mask head: h @ w_mask, softmax(16), transpose ----------
// Block = 64 pixels x 4 slots. Slot s handles channels c == s (mod 4)
// (coalesced global h reads, conflict-light LDS w reads). Cross-slot reduce
// through LDS, softmax over 16 via 2 shuffles, strided-plane writes.
__global__ __launch_bounds__(256) void mask_kernel(
    const float* __restrict__ h, const float* __restrict__ wm,
    float* __restrict__ out)
{
    __shared__ float wls[QQ * MM];      // 8 KB, [c][m] native layout
    __shared__ float part[64][4][20];   // [px][slot][16m + pad]
    const int t = threadIdx.x;
    for (int idx = t; idx < QQ * MM / 4; idx += 256)
        ((float4*)wls)[idx] = ((const float4*)wm)[idx];
    const int blk = blockIdx.x;         // 512
    const int b   = blk >> 8;
    const int n0  = (blk & 255) << 6;
    const int px  = t >> 2, s = t & 3;
    const float* hr = h + (((size_t)(b << 14) + n0 + px) << 7);

    // load this thread's 32 interleaved channels: c = s + 4k
    float hv[32];
    #pragma unroll
    for (int k = 0; k < 32; k++) hv[k] = hr[s + (k << 2)];
    __syncthreads();

    float4 a0 = {0,0,0,0}, a1 = a0, a2 = a0, a3 = a0;
    #pragma unroll
    for (int k = 0; k < 32; k++) {
        const float4* wrow = (const float4*)(wls + ((s + (k << 2)) << 4));
        float v = hv[k];
        float4 w0 = wrow[0], w1 = wrow[1], w2 = wrow[2], w3 = wrow[3];
        a0.x += v * w0.x; a0.y += v * w0.y; a0.z += v * w0.z; a0.w += v * w0.w;
        a1.x += v * w1.x; a1.y += v * w1.y; a1.z += v * w1.z; a1.w += v * w1.w;
        a2.x += v * w2.x; a2.y += v * w2.y; a2.z += v * w2.z; a2.w += v * w2.w;
        a3.x += v * w3.x; a3.y += v * w3.y; a3.z += v * w3.z; a3.w += v * w3.w;
    }
    *(float4*)&part[px][s][0]  = a0;
    *(float4*)&part[px][s][4]  = a1;
    *(float4*)&part[px][s][8]  = a2;
    *(float4*)&part[px][s][12] = a3;
    __syncthreads();

    // thread (px,s) reduces m-quad s over the 4 slots
    float4 r = {0,0,0,0};
    #pragma unroll
    for (int ss = 0; ss < 4; ss++) {
        float4 v = *(const float4*)&part[px][ss][s << 2];
        r.x += v.x; r.y += v.y; r.z += v.z; r.w += v.w;
    }
    float mx = fmaxf(fmaxf(r.x, r.y), fmaxf(r.z, r.w));
    mx = fmaxf(mx, __shfl_xor(mx, 1, 64));
    mx = fmaxf(mx, __shfl_xor(mx, 2, 64));
    float4 e = {expf(r.x - mx), expf(r.y - mx), expf(r.z - mx), expf(r.w - mx)};
    float ls = e.x + e.y + e.z + e.w;
    ls += __shfl_xor(ls, 1, 64);
    ls += __shfl_xor(ls, 2, 64);
    float inv = 1.0f / ls;
    float* ob = out + (((size_t)((b << 4) + (s << 2))) << 14) + n0 + px;
    ob[0]           = e.x * inv;
    ob[1 << 14]     = e.y * inv;
    ob[2 << 14]     = e.z * inv;
    ob[3 * (1 << 14)] = e.w * inv;
}

extern "C" void kernel_launch(void* const* d_in, const int* in_sizes, int n_in,
                              void* d_out, int out_size, void* d_ws, size_t ws_size,
                              hipStream_t stream)
{
    const float* x     = (const float*)d_in[0];
    // d_in[1] = edges (int32) -- unused: row/col are analytic
    const float* w1    = (const float*)d_in[2];
    const float* b1    = (const float*)d_in[3];
    const float* w2    = (const float*)d_in[4];
    const float* b2    = (const float*)d_in[5];
    const float* wk    = (const float*)d_in[6];
    const float* bk    = (const float*)d_in[7];
    const float* wq    = (const float*)d_in[8];
    const float* hinit = (const float*)d_in[9];
    const float* wm    = (const float*)d_in[10];
    float* out = (float*)d_out;

    char* ws = (char*)d_ws;
    size_t off = 0;
    auto alloc = [&](size_t bytes) -> void* {
        void* p = ws + off;
        off += (bytes + 255) & ~(size_t)255;
        return p;
    };
    float* feat1 = (float*)alloc((size_t)NBATCH * NPIX * DD * 4);
    float* feat2 = (float*)alloc((size_t)NBATCH * NPIX * DD * 4);
    float* ksb   = (float*)alloc((size_t)NBATCH * NPIX * DD * 4);
    float* qsb   = (float*)alloc((size_t)NBATCH * NPIX * DD * 4);
    float* knorm = (float*)alloc((size_t)NBATCH * NPIX * 4);
    float* qnorm = (float*)alloc((size_t)NBATCH * NPIX * 4);
    float* wT    = (float*)alloc((size_t)NBATCH * NPIX * 32 * 4);
    float* sums  = (float*)alloc(256);
    float* hA    = (float*)alloc((size_t)NBATCH * NPIX * QQ * 4);
    float* hB    = (float*)alloc((size_t)NBATCH * NPIX * QQ * 4);

    hipMemsetAsync(sums, 0, 2 * sizeof(float), stream);

    conv1_kernel<<<512, 256, 0, stream>>>(x, w1, b1, feat1);
    conv2_kernel<<<512, 256, 0, stream>>>(feat1, w2, b2, feat2);
    kq_kernel<<<4096, 256, 0, stream>>>(feat2, wk, bk, wq, ksb, qsb, knorm, qnorm);
    edge_kernel<<<512, 256, 0, stream>>>(ksb, qsb, knorm, qnorm, wT, sums);

    const float* src = hinit;
    float* dst = hA;
    for (int it = 0; it < 32; it++) {
        prop_kernel<<<512, 256, 0, stream>>>(src, dst, wT, sums);
        src = dst;
        dst = (dst == hA) ? hB : hA;
    }
    mask_kernel<<<512, 256, 0, stream>>>(src, wm, out);
}